// Round 12
// baseline (202.627 us; speedup 1.0000x reference)
//
#include <hip/hip_runtime.h>

#define IYD 192
#define IZD 160
#define PLANE 30720        // IYD*IZD
#define VOLSZ 4915200      // 160*PLANE
#define YG 191
#define ZG 159

// LDS float layout (9052 floats = 36208 B), v7 bank residues per buffer:
// raw[2 slot][2v][15][44] @0      slot = plane&1 (pair base even -> static)
// ZBA @2668 (res12)  DBA @3748 (res4)   : plane A z-stage
// ZBB2 @4844 (res12) DBB2 @5924 (res4)  : plane B z-stage
// TBA @7004 (res28)  WBA @7516 (res28)  : plane A y-stage [2v][8][32]
// TBB2 @8028 (res28) WBB2 @8540 (res28) : plane B y-stage
#define RAWV 660
#define RAWR 44
#define RAWSLOT 1320
#define ZBA 2668
#define DBA 3748
#define ZBB2 4844
#define DBB2 5924
#define TBA 7004
#define WBA 7516
#define TBB2 8028
#define WBB2 8540
#define ZDV 540
#define ZDR 36
#define LDSF 9052

#define NVOX_INV (1.0f / 9657342.0f)   // 2*159*191*159

__device__ __forceinline__ float4 f4scale(float4 a, float s) {
    return make_float4(a.x * s, a.y * s, a.z * s, a.w * s);
}

__global__ __launch_bounds__(256, 4) void grad_sim_v12(
    const float* __restrict__ Ii, const float* __restrict__ Ji,
    float* __restrict__ out)
{
    __shared__ __align__(16) float lds[LDSF];
    const int tid = threadIdx.x;
    const int z0 = (int)blockIdx.x * 32;
    const int y0 = (int)blockIdx.y * 8;
    const int seg = blockIdx.z & 3;
    const int bat = blockIdx.z >> 2;
    const int s0 = seg * 40;
    const int a0 = (seg == 0) ? 0 : (s0 - 3);
    const int aLast = (seg == 3) ? 159 : (s0 + 43);

    const float* __restrict__ bI = Ii + (size_t)bat * VOLSZ;
    const float* __restrict__ bJ = Ji + (size_t)bat * VOLSZ;

    // ---- per-thread float4 halo-land tasks (slot-relative): 2v x 15 x 10 = 300 ----
    const float* gq0; const float* gq1;
    int lq0, lq1; float mq0, mq1;
    {
        int q = tid;
        int v = q / 150; int rr = q - v * 150;
        int row = rr / 10; int qd = rr - row * 10;
        int iy = y0 - 3 + row; int izb = z0 - 4 + 4 * qd;
        bool ok = ((unsigned)iy < IYD) && (izb >= 0) && (izb + 3 <= 159);
        int iyc = min(max(iy, 0), IYD - 1); int izc = min(max(izb, 0), 156);
        gq0 = (v ? bJ : bI) + (iyc * IZD + izc);
        lq0 = v * RAWV + row * RAWR + 4 * qd;
        mq0 = ok ? 1.f : 0.f;
    }
    {
        int q = 256 + tid;
        int v = q / 150; int rr = q - v * 150;
        int row = rr / 10; int qd = rr - row * 10;
        int iy = y0 - 3 + row; int izb = z0 - 4 + 4 * qd;
        bool ok = ((unsigned)iy < IYD) && (izb >= 0) && (izb + 3 <= 159);
        int iyc = min(max(iy, 0), IYD - 1); int izc = min(max(izb, 0), 156);
        gq1 = (v ? bJ : bI) + (iyc * IZD + izc);
        lq1 = v * RAWV + row * RAWR + 4 * qd;
        mq1 = ok ? 1.f : 0.f;
    }

    // ---- E1 decode: lanes 0..119 plane A, 128..247 plane B ----
    const int pp = tid >> 7;
    const int rem = tid & 127;
    const bool doZ = rem < 120;
    const int e1t = doZ ? rem : 0;
    const int zv = (e1t >= 60) ? 1 : 0;
    const int rr1 = e1t - 60 * zv;
    const int zr = rr1 >> 2;
    const int zq = rr1 & 3;
    const bool zlo = (z0 == 0) && (zq == 0);
    const bool zhi = (z0 == 128) && (zq == 3);
    const int rawRd = pp * RAWSLOT + zv * RAWV + zr * RAWR + 8 * zq;
    const int zbW = (pp ? ZBB2 : ZBA) + zv * ZDV + zr * ZDR + 8 * zq;
    const int dbW = (pp ? DBB2 : DBA) + zv * ZDV + zr * ZDR + 8 * zq;

    // ---- E2 decode: lanes 0..63 plane A, 64..127 plane B (v7 body) ----
    const int pp2 = (tid >> 6) & 1;
    const bool doY = tid < 128;
    const int et = tid & 63;
    const int e2half = et & 1;
    const int e2c = et >> 1;
    const int e2zq = e2c & 7;
    const int e2f = (e2c >> 3) & 1;
    const int e2v = e2c >> 4;
    const int e2base = (e2f ? (pp2 ? DBB2 : DBA) : (pp2 ? ZBB2 : ZBA)) + e2v * ZDV + 4 * e2zq;
    const int e2out = (e2f ? (pp2 ? WBB2 : WBA) : (pp2 ? TBB2 : TBA)) + e2v * 256 + 4 * e2zq;
    const float mlo = (y0 == 0) ? 0.f : 1.f;
    const float mhi = (y0 == 184) ? 0.f : 1.f;

    // ---- E3 per-thread column (relative offsets) ----
    const int oy = tid >> 5;
    const int oz = tid & 31;
    const int ygl = y0 + oy;
    const int vmax = min(3, 190 - ygl);
    const int vmin = max(-3, -ygl);
    const int vHiRel = (oy + vmax + 4) * ZDR + oz;
    const int vLoRel = (oy + vmin + 3) * ZDR + oz;
    const bool okyz = (ygl < YG) && ((z0 + oz) < ZG);

    // x rings (static indices only)
    float Tr[2][8], Vr[2][8], Wr[2][8], Sdy[2], Sdz[2];
#pragma unroll
    for (int v = 0; v < 2; ++v) {
#pragma unroll
        for (int j = 0; j < 8; ++j) { Tr[v][j] = 0.f; Vr[v][j] = 0.f; Wr[v][j] = 0.f; }
        Sdy[v] = 0.f; Sdz[v] = 0.f;
    }
    float acc = 0.f;

    // ---- prologue: land plane a0 (and a0+1 if a0 even) ----
    {
        const size_t pb0 = (size_t)a0 * PLANE;
        if (a0 & 1) {
            *(float4*)&lds[RAWSLOT + lq0] = f4scale(*(const float4*)(gq0 + pb0), mq0);
            if (tid < 44)
                *(float4*)&lds[RAWSLOT + lq1] = f4scale(*(const float4*)(gq1 + pb0), mq1);
        } else {
            *(float4*)&lds[lq0] = f4scale(*(const float4*)(gq0 + pb0), mq0);
            if (tid < 44)
                *(float4*)&lds[lq1] = f4scale(*(const float4*)(gq1 + pb0), mq1);
            const size_t pb1 = (size_t)(a0 + 1) * PLANE;
            *(float4*)&lds[RAWSLOT + lq0] = f4scale(*(const float4*)(gq0 + pb1), mq0);
            if (tid < 44)
                *(float4*)&lds[RAWSLOT + lq1] = f4scale(*(const float4*)(gq1 + pb1), mq1);
        }
    }
    __syncthreads();

    for (int ag = (a0 & ~7); ag <= aLast; ag += 8) {
#pragma unroll
        for (int uu = 0; uu < 4; ++uu) {
            const int u = 2 * uu;
            const int a = ag + u;
            if (a + 1 < a0 || a > aLast) continue;   // pair fully inactive (uniform)
            const bool actA = (a >= a0) && (a <= aLast);
            const bool actB = (a + 1 >= a0) && (a + 1 <= aLast);
            const bool landA = (a + 2 <= aLast);
            const bool landB = (a + 3 <= aLast);

            // ---- issue prefetch of planes a+2, a+3 ----
            float4 pfA0, pfA1, pfB0, pfB1;
            if (landA) {
                const size_t pb = (size_t)(a + 2) * PLANE;
                pfA0 = *(const float4*)(gq0 + pb);
                if (tid < 44) pfA1 = *(const float4*)(gq1 + pb);
            }
            if (landB) {
                const size_t pb = (size_t)(a + 3) * PLANE;
                pfB0 = *(const float4*)(gq0 + pb);
                if (tid < 44) pfB1 = *(const float4*)(gq1 + pb);
            }

            // ---- E1: z-stage (4 waves, one plane each) ----
            if (doZ && (pp ? actB : actA)) {
                float C[16];
                const float4* rb = (const float4*)&lds[rawRd];
#pragma unroll
                for (int q = 0; q < 4; ++q) ((float4*)C)[q] = rb[q];
                float D[8];
#pragma unroll
                for (int i = 0; i < 8; ++i) D[i] = C[i + 8] - C[i + 1];
                if (zlo) { D[0] = C[8] - C[4]; D[1] = C[9] - C[4]; D[2] = C[10] - C[4]; }
                if (zhi) { D[4] = C[11] - C[5]; D[5] = C[11] - C[6];
                           D[6] = C[11] - C[7]; D[7] = C[11] - C[8]; }
                if (zlo) { C[2] = 0.f; C[3] = 0.f; C[4] = 0.f; }
                float Z[8];
                float w = C[2] + C[3] + C[4] + C[5] + C[6] + C[7] + C[8];
                Z[0] = w;
#pragma unroll
                for (int m = 1; m < 8; ++m) { w += C[m + 8] - C[m + 1]; Z[m] = w; }
                float4* zb = (float4*)&lds[zbW];
                zb[0] = make_float4(Z[0], Z[1], Z[2], Z[3]);
                zb[1] = make_float4(Z[4], Z[5], Z[6], Z[7]);
                float4* db = (float4*)&lds[dbW];
                db[0] = make_float4(D[0], D[1], D[2], D[3]);
                db[1] = make_float4(D[4], D[5], D[6], D[7]);
            }
            __syncthreads();

            // ---- E2: y-slide (2 waves, one plane each; v7 body) ----
            if (doY && (pp2 ? actB : actA)) {
                float4 r[11];
                const int r0 = e2half ? 4 : 1;
#pragma unroll
                for (int i = 0; i < 11; ++i)
                    r[i] = *(const float4*)&lds[e2base + (r0 + i) * ZDR];
                if (e2half == 0) {
                    r[0].x *= mlo; r[0].y *= mlo; r[0].z *= mlo; r[0].w *= mlo;
                    r[1].x *= mlo; r[1].y *= mlo; r[1].z *= mlo; r[1].w *= mlo;
                    r[2].x *= mlo; r[2].y *= mlo; r[2].z *= mlo; r[2].w *= mlo;
                    r[10].x *= mhi; r[10].y *= mhi; r[10].z *= mhi; r[10].w *= mhi;
                    float4 w;
                    w.x = r[0].x + r[1].x + r[2].x + r[3].x + r[4].x + r[5].x + r[6].x;
                    w.y = r[0].y + r[1].y + r[2].y + r[3].y + r[4].y + r[5].y + r[6].y;
                    w.z = r[0].z + r[1].z + r[2].z + r[3].z + r[4].z + r[5].z + r[6].z;
                    w.w = r[0].w + r[1].w + r[2].w + r[3].w + r[4].w + r[5].w + r[6].w;
                    *(float4*)&lds[e2out] = w;
#pragma unroll
                    for (int m = 1; m < 4; ++m) {
                        w.x += r[m + 6].x - r[m - 1].x;
                        w.y += r[m + 6].y - r[m - 1].y;
                        w.z += r[m + 6].z - r[m - 1].z;
                        w.w += r[m + 6].w - r[m - 1].w;
                        *(float4*)&lds[e2out + m * 32] = w;
                    }
                } else {
                    r[7].x *= mhi; r[7].y *= mhi; r[7].z *= mhi; r[7].w *= mhi;
                    r[8].x *= mhi; r[8].y *= mhi; r[8].z *= mhi; r[8].w *= mhi;
                    r[9].x *= mhi; r[9].y *= mhi; r[9].z *= mhi; r[9].w *= mhi;
                    r[10].x *= mhi; r[10].y *= mhi; r[10].z *= mhi; r[10].w *= mhi;
                    float4 w;
                    w.x = r[1].x + r[2].x + r[3].x + r[4].x + r[5].x + r[6].x + r[7].x;
                    w.y = r[1].y + r[2].y + r[3].y + r[4].y + r[5].y + r[6].y + r[7].y;
                    w.z = r[1].z + r[2].z + r[3].z + r[4].z + r[5].z + r[6].z + r[7].z;
                    w.w = r[1].w + r[2].w + r[3].w + r[4].w + r[5].w + r[6].w + r[7].w;
                    *(float4*)&lds[e2out + 4 * 32] = w;
#pragma unroll
                    for (int m = 1; m < 4; ++m) {
                        w.x += r[m + 7].x - r[m].x;
                        w.y += r[m + 7].y - r[m].y;
                        w.z += r[m + 7].z - r[m].z;
                        w.w += r[m + 7].w - r[m].w;
                        *(float4*)&lds[e2out + (4 + m) * 32] = w;
                    }
                }
            }
            __syncthreads();

            // ---- E3: two ring pushes (plane A then B) ----
            if (actA) {
                float tI = lds[TBA + tid];
                float tJ = lds[TBA + 256 + tid];
                float wI = lds[WBA + tid];
                float wJ = lds[WBA + 256 + tid];
                float vI = lds[ZBA + vHiRel] - lds[ZBA + vLoRel];
                float vJ = lds[ZBA + ZDV + vHiRel] - lds[ZBA + ZDV + vLoRel];
                if (a == a0) { vI = 0.f; vJ = 0.f; wI = 0.f; wJ = 0.f; }
                const int p = u;                 // compile-time
                const int p1 = (u + 1) & 7;
                float hdxI = tI - Tr[0][p1];
                float hdxJ = tJ - Tr[1][p1];
                Sdy[0] += vI - Vr[0][p1]; Vr[0][p] = vI;
                Sdy[1] += vJ - Vr[1][p1]; Vr[1][p] = vJ;
                Sdz[0] += wI - Wr[0][p1]; Wr[0][p] = wI;
                Sdz[1] += wJ - Wr[1][p1]; Wr[1][p] = wJ;
                Tr[0][p] = tI; Tr[1][p] = tJ;
                if (u == 0 && a == 0) {          // seed clamped prefix T[0] for x=0,1,2
                    Tr[0][5] = tI; Tr[0][6] = tI; Tr[0][7] = tI;
                    Tr[1][5] = tJ; Tr[1][6] = tJ; Tr[1][7] = tJ;
                }
                if (a >= s0 + 4) {
                    float cross = fabsf(hdxI * hdxJ + Sdy[0] * Sdy[1] + Sdz[0] * Sdz[1]) + 0.01f;
                    float dI = hdxI * hdxI + Sdy[0] * Sdy[0] + Sdz[0] * Sdz[0] + 0.01f;
                    float dJ = hdxJ * hdxJ + Sdy[1] * Sdy[1] + Sdz[1] * Sdz[1] + 0.01f;
                    float val = cross * rsqrtf(dI * dJ);
                    if (okyz) acc += val;
                }
            }
            if (actB) {
                float tI = lds[TBB2 + tid];
                float tJ = lds[TBB2 + 256 + tid];
                float wI = lds[WBB2 + tid];
                float wJ = lds[WBB2 + 256 + tid];
                float vI = lds[ZBB2 + vHiRel] - lds[ZBB2 + vLoRel];
                float vJ = lds[ZBB2 + ZDV + vHiRel] - lds[ZBB2 + ZDV + vLoRel];
                if (a + 1 == a0) { vI = 0.f; vJ = 0.f; wI = 0.f; wJ = 0.f; }
                const int p = u + 1;             // compile-time, 1..7 (never 0 -> no seed)
                const int p1 = (u + 2) & 7;
                float hdxI = tI - Tr[0][p1];
                float hdxJ = tJ - Tr[1][p1];
                Sdy[0] += vI - Vr[0][p1]; Vr[0][p] = vI;
                Sdy[1] += vJ - Vr[1][p1]; Vr[1][p] = vJ;
                Sdz[0] += wI - Wr[0][p1]; Wr[0][p] = wI;
                Sdz[1] += wJ - Wr[1][p1]; Wr[1][p] = wJ;
                Tr[0][p] = tI; Tr[1][p] = tJ;
                if (a + 1 >= s0 + 4) {
                    float cross = fabsf(hdxI * hdxJ + Sdy[0] * Sdy[1] + Sdz[0] * Sdz[1]) + 0.01f;
                    float dI = hdxI * hdxI + Sdy[0] * Sdy[0] + Sdz[0] * Sdz[0] + 0.01f;
                    float dJ = hdxJ * hdxJ + Sdy[1] * Sdy[1] + Sdz[1] * Sdz[1] + 0.01f;
                    float val = cross * rsqrtf(dI * dJ);
                    if (okyz) acc += val;
                }
            }

            // ---- land prefetched planes a+2 (slot0), a+3 (slot1) ----
            if (landA) {
                *(float4*)&lds[lq0] = f4scale(pfA0, mq0);
                if (tid < 44) *(float4*)&lds[lq1] = f4scale(pfA1, mq1);
            }
            if (landB) {
                *(float4*)&lds[RAWSLOT + lq0] = f4scale(pfB0, mq0);
                if (tid < 44) *(float4*)&lds[RAWSLOT + lq1] = f4scale(pfB1, mq1);
            }
            __syncthreads();
        }
    }

    // ---- register-only tail (seg 3): x = 156,157,158 ----
    if (seg == 3) {
#pragma unroll
        for (int tt = 0; tt < 3; ++tt) {
            const int sl = tt + 1;               // planes 153,154,155
            float hdxI = Tr[0][7] - Tr[0][sl];   // T[159] - T[x-3]
            float hdxJ = Tr[1][7] - Tr[1][sl];
            Sdy[0] -= Vr[0][sl]; Sdy[1] -= Vr[1][sl];
            Sdz[0] -= Wr[0][sl]; Sdz[1] -= Wr[1][sl];
            float cross = fabsf(hdxI * hdxJ + Sdy[0] * Sdy[1] + Sdz[0] * Sdz[1]) + 0.01f;
            float dI = hdxI * hdxI + Sdy[0] * Sdy[0] + Sdz[0] * Sdz[0] + 0.01f;
            float dJ = hdxJ * hdxJ + Sdy[1] * Sdy[1] + Sdz[1] * Sdz[1] + 0.01f;
            float val = cross * rsqrtf(dI * dJ);
            if (okyz) acc += val;
        }
    }

    // ---- block reduce + atomic ----
#pragma unroll
    for (int off = 32; off > 0; off >>= 1) acc += __shfl_down(acc, off, 64);
    __syncthreads();
    if ((tid & 63) == 0) lds[tid >> 6] = acc;
    __syncthreads();
    if (tid == 0)
        atomicAdd(out, (lds[0] + lds[1] + lds[2] + lds[3]) * NVOX_INV);
}

extern "C" void kernel_launch(void* const* d_in, const int* in_sizes, int n_in,
                              void* d_out, int out_size, void* d_ws, size_t ws_size,
                              hipStream_t stream) {
    const float* Ii = (const float*)d_in[0];
    const float* Ji = (const float*)d_in[1];
    float* out = (float*)d_out;
    hipMemsetAsync(d_out, 0, sizeof(float) * (out_size > 0 ? out_size : 1), stream);
    dim3 grid(5, 24, 8);   // z-tiles(32) x y-tiles(8) x (4 x-segments * 2 batches)
    grad_sim_v12<<<grid, dim3(256), 0, stream>>>(Ii, Ji, out);
}